// Round 2
// baseline (1655.230 us; speedup 1.0000x reference)
//
#include <hip/hip_runtime.h>

#define BATCH 8
#define GDIM 32
#define NCELL (GDIM * GDIM * GDIM)
#define NG (2 * BATCH)          // grids: g = cloud*BATCH + b; cloud 0 = y_true, 1 = y_pred
#define THREADS 256
#define NPART 256

// ---------- helpers ----------
__device__ __forceinline__ float axdist(float v, float c0, float cs) {
    // distance from v to interval [c0, c0+cs]
    return fmaxf(fmaxf(c0 - v, v - (c0 + cs)), 0.f);
}

// ---------- 1. per-grid bounding box ----------
__global__ __launch_bounds__(THREADS) void bbox_kernel(
    const float* __restrict__ ytrue, const float* __restrict__ ypred,
    int N, float* __restrict__ bbox /* NG*6: lo3,hi3 */)
{
    int g = blockIdx.x;
    int cloud = g / BATCH, b = g % BATCH;
    const float* src = (cloud ? ypred : ytrue) + (size_t)b * N * 3;
    float mnx = 1e30f, mny = 1e30f, mnz = 1e30f;
    float mxx = -1e30f, mxy = -1e30f, mxz = -1e30f;
    for (int i = threadIdx.x; i < N; i += THREADS) {
        const float* p = src + (size_t)i * 3;
        float x = p[0], y = p[1], z = p[2];
        mnx = fminf(mnx, x); mny = fminf(mny, y); mnz = fminf(mnz, z);
        mxx = fmaxf(mxx, x); mxy = fmaxf(mxy, y); mxz = fmaxf(mxz, z);
    }
#pragma unroll
    for (int off = 32; off > 0; off >>= 1) {
        mnx = fminf(mnx, __shfl_down(mnx, off, 64));
        mny = fminf(mny, __shfl_down(mny, off, 64));
        mnz = fminf(mnz, __shfl_down(mnz, off, 64));
        mxx = fmaxf(mxx, __shfl_down(mxx, off, 64));
        mxy = fmaxf(mxy, __shfl_down(mxy, off, 64));
        mxz = fmaxf(mxz, __shfl_down(mxz, off, 64));
    }
    __shared__ float sm[6][THREADS / 64];
    int w = threadIdx.x >> 6, l = threadIdx.x & 63;
    if (l == 0) {
        sm[0][w] = mnx; sm[1][w] = mny; sm[2][w] = mnz;
        sm[3][w] = mxx; sm[4][w] = mxy; sm[5][w] = mxz;
    }
    __syncthreads();
    if (threadIdx.x == 0) {
        float r[6];
#pragma unroll
        for (int k = 0; k < 6; ++k) {
            float v = sm[k][0];
            for (int i = 1; i < THREADS / 64; ++i)
                v = (k < 3) ? fminf(v, sm[k][i]) : fmaxf(v, sm[k][i]);
            r[k] = v;
        }
#pragma unroll
        for (int k = 0; k < 6; ++k) bbox[g * 6 + k] = r[k];
    }
}

// cell index from coords, consistent across hist/scatter/search
__device__ __forceinline__ void gridParams(const float* bb, float* lo, float* inv, float* cs) {
#pragma unroll
    for (int d = 0; d < 3; ++d) {
        lo[d] = bb[d];
        float span = bb[3 + d] - bb[d];
        float iv = (float)GDIM / (span * (1.f + 1e-6f) + 1e-12f);
        inv[d] = iv;
        cs[d] = 1.f / iv;
    }
}

__device__ __forceinline__ int cellIdx(float x, float y, float z,
                                       const float* lo, const float* inv,
                                       int* cx, int* cy, int* cz) {
    int ix = min(max((int)floorf((x - lo[0]) * inv[0]), 0), GDIM - 1);
    int iy = min(max((int)floorf((y - lo[1]) * inv[1]), 0), GDIM - 1);
    int iz = min(max((int)floorf((z - lo[2]) * inv[2]), 0), GDIM - 1);
    *cx = ix; *cy = iy; *cz = iz;
    return (iz * GDIM + iy) * GDIM + ix;
}

// ---------- 2. histogram ----------
__global__ __launch_bounds__(THREADS) void hist_kernel(
    const float* __restrict__ ytrue, const float* __restrict__ ypred,
    int N, const float* __restrict__ bbox, unsigned* __restrict__ cnt)
{
    int i = blockIdx.x * THREADS + threadIdx.x;
    if (i >= NG * N) return;
    int g = i / N, j = i % N;
    int cloud = g / BATCH, b = g % BATCH;
    const float* p = (cloud ? ypred : ytrue) + ((size_t)b * N + j) * 3;
    float lo[3], inv[3], cs[3];
    gridParams(bbox + g * 6, lo, inv, cs);
    int cx, cy, cz;
    int cid = cellIdx(p[0], p[1], p[2], lo, inv, &cx, &cy, &cz);
    atomicAdd(&cnt[g * NCELL + cid], 1u);
}

// ---------- 3. per-grid exclusive scan, pack (start<<16)|count ----------
__global__ __launch_bounds__(1024) void scan_kernel(
    const unsigned* __restrict__ cnt, unsigned* __restrict__ sc)
{
    int g = blockIdx.x;
    const unsigned* c = cnt + (size_t)g * NCELL;
    unsigned* out = sc + (size_t)g * NCELL;
    const int per = NCELL / 1024;   // 32
    int base = threadIdx.x * per;
    unsigned s = 0;
    for (int j = 0; j < per; ++j) s += c[base + j];
    __shared__ unsigned sd[1024];
    sd[threadIdx.x] = s;
    __syncthreads();
    for (int off = 1; off < 1024; off <<= 1) {
        unsigned t = (threadIdx.x >= off) ? sd[threadIdx.x - off] : 0u;
        __syncthreads();
        sd[threadIdx.x] += t;
        __syncthreads();
    }
    unsigned run = sd[threadIdx.x] - s;   // exclusive prefix
    for (int j = 0; j < per; ++j) {
        unsigned cc = c[base + j];
        out[base + j] = (run << 16) | cc;
        run += cc;
    }
}

// ---------- 4. scatter into sorted, pack {x,y,z,|p|^2} ----------
__global__ __launch_bounds__(THREADS) void scatter_kernel(
    const float* __restrict__ ytrue, const float* __restrict__ ypred,
    int N, const float* __restrict__ bbox, const unsigned* __restrict__ sc,
    unsigned* __restrict__ fill, float4* __restrict__ sorted)
{
    int i = blockIdx.x * THREADS + threadIdx.x;
    if (i >= NG * N) return;
    int g = i / N, j = i % N;
    int cloud = g / BATCH, b = g % BATCH;
    const float* p = (cloud ? ypred : ytrue) + ((size_t)b * N + j) * 3;
    float x = p[0], y = p[1], z = p[2];
    float lo[3], inv[3], cs[3];
    gridParams(bbox + g * 6, lo, inv, cs);
    int cx, cy, cz;
    int cid = cellIdx(x, y, z, lo, inv, &cx, &cy, &cz);
    unsigned st = sc[g * NCELL + cid] >> 16;
    unsigned pos = st + atomicAdd(&fill[g * NCELL + cid], 1u);
    sorted[(size_t)g * N + pos] =
        make_float4(x, y, z, fmaf(x, x, fmaf(y, y, z * z)));
}

// ---------- 5. exact NN via expanding Chebyshev shells ----------
__global__ __launch_bounds__(THREADS) void nn_kernel(
    const float4* __restrict__ sorted, const unsigned* __restrict__ sc,
    const float* __restrict__ bbox, int N, float* __restrict__ res)
{
    int i = blockIdx.x * THREADS + threadIdx.x;
    if (i >= NG * N) return;
    int gq = i / N;
    int cloud = gq / BATCH, b = gq % BATCH;
    int gr = (1 - cloud) * BATCH + b;

    float4 q = sorted[i];
    float lo[3], inv[3], cs[3];
    gridParams(bbox + gr * 6, lo, inv, cs);
    int cx, cy, cz;
    cellIdx(q.x, q.y, q.z, lo, inv, &cx, &cy, &cz);

    const unsigned* C = sc + (size_t)gr * NCELL;
    const float4* P = sorted + (size_t)gr * N;

    float qx2 = -2.f * q.x, qy2 = -2.f * q.y, qz2 = -2.f * q.z;
    float q2 = q.w;
    float best = 1e30f;   // t-space: d2 = q2 + best

    auto visit = [&](int x, int y, int z, float dyz2) {
        float dxx = axdist(q.x, lo[0] + x * cs[0], cs[0]);
        float lb2 = fmaf(dxx, dxx, dyz2);
        unsigned scv = C[(z * GDIM + y) * GDIM + x];
        unsigned cn = scv & 0xffffu;
        if (cn != 0u && lb2 * 0.998f < q2 + best) {
            unsigned st = scv >> 16;
            for (unsigned jj = st; jj < st + cn; ++jj) {
                float4 p = P[jj];
                float t = fmaf(qx2, p.x, fmaf(qy2, p.y, fmaf(qz2, p.z, p.w)));
                best = fminf(best, t);
            }
        }
    };

    for (int r = 0; r <= 2 * GDIM; ++r) {
        int x0 = max(cx - r, 0), x1 = min(cx + r, GDIM - 1);
        int y0 = max(cy - r, 0), y1 = min(cy + r, GDIM - 1);
        int z0 = max(cz - r, 0), z1 = min(cz + r, GDIM - 1);
        for (int z = z0; z <= z1; ++z) {
            bool zf = (z == cz - r) || (z == cz + r);
            float dzz = axdist(q.z, lo[2] + z * cs[2], cs[2]);
            float dz2 = dzz * dzz;
            for (int y = y0; y <= y1; ++y) {
                bool yf = (y == cy - r) || (y == cy + r);
                float dyy = axdist(q.y, lo[1] + y * cs[1], cs[1]);
                float dyz2 = fmaf(dyy, dyy, dz2);
                if (zf || yf) {
                    for (int x = x0; x <= x1; ++x) visit(x, y, z, dyz2);
                } else {
                    if (cx - r >= 0)              visit(cx - r, y, z, dyz2);
                    if (r > 0 && cx + r <= GDIM - 1) visit(cx + r, y, z, dyz2);
                }
            }
        }
        bool covered = (x0 == 0 && y0 == 0 && z0 == 0 &&
                        x1 == GDIM - 1 && y1 == GDIM - 1 && z1 == GDIM - 1);
        if (covered) break;
        // lower bound to any cell outside the radius-r box
        float dlx = q.x - (lo[0] + (cx - r) * cs[0]);
        float dhx = (lo[0] + (cx + r + 1) * cs[0]) - q.x;
        float dly = q.y - (lo[1] + (cy - r) * cs[1]);
        float dhy = (lo[1] + (cy + r + 1) * cs[1]) - q.y;
        float dlz = q.z - (lo[2] + (cz - r) * cs[2]);
        float dhz = (lo[2] + (cz + r + 1) * cs[2]) - q.z;
        float m = fminf(fminf(fminf(dlx, dhx), fminf(dly, dhy)), fminf(dlz, dhz));
        if (m > 0.f) {
            float mb = m * m * 0.998f;
            if (mb >= q2 + best) break;
        }
    }
    res[i] = fmaxf(0.f, q2 + best);
}

// ---------- 6. deterministic sum reduction ----------
__global__ __launch_bounds__(THREADS) void reduce1_kernel(
    const float* __restrict__ vals, int n, float* __restrict__ partial)
{
    __shared__ float sd[THREADS / 64];
    float s = 0.f;
    for (int i = blockIdx.x * THREADS + threadIdx.x; i < n;
         i += gridDim.x * THREADS)
        s += vals[i];
#pragma unroll
    for (int off = 32; off > 0; off >>= 1) s += __shfl_down(s, off, 64);
    int lane = threadIdx.x & 63, w = threadIdx.x >> 6;
    if (lane == 0) sd[w] = s;
    __syncthreads();
    if (threadIdx.x == 0) {
        float t = 0.f;
#pragma unroll
        for (int i = 0; i < THREADS / 64; ++i) t += sd[i];
        partial[blockIdx.x] = t;
    }
}

__global__ __launch_bounds__(THREADS) void reduce2_kernel(
    const float* __restrict__ partial, int n, float invB, float* __restrict__ out)
{
    __shared__ float sd[THREADS / 64];
    float s = 0.f;
    for (int i = threadIdx.x; i < n; i += THREADS) s += partial[i];
#pragma unroll
    for (int off = 32; off > 0; off >>= 1) s += __shfl_down(s, off, 64);
    int lane = threadIdx.x & 63, w = threadIdx.x >> 6;
    if (lane == 0) sd[w] = s;
    __syncthreads();
    if (threadIdx.x == 0) {
        float t = 0.f;
        for (int i = 0; i < THREADS / 64; ++i) t += sd[i];
        out[0] = t * invB;
    }
}

extern "C" void kernel_launch(void* const* d_in, const int* in_sizes, int n_in,
                              void* d_out, int out_size, void* d_ws, size_t ws_size,
                              hipStream_t stream)
{
    const float* ytrue = (const float*)d_in[0];
    const float* ypred = (const float*)d_in[1];
    int N = in_sizes[0] / (BATCH * 3);          // 8192
    size_t totalPts = (size_t)NG * N;           // 131072

    char* ws = (char*)d_ws;
    float4* sorted = (float4*)ws;          ws += totalPts * sizeof(float4);      // 2 MB (16B aligned first)
    unsigned* cnt  = (unsigned*)ws;        ws += (size_t)NG * NCELL * 4;         // 2 MB (also reused as fill)
    unsigned* sc   = (unsigned*)ws;        ws += (size_t)NG * NCELL * 4;         // 2 MB
    float* res     = (float*)ws;           ws += totalPts * sizeof(float);       // 0.5 MB
    float* bbox    = (float*)ws;           ws += NG * 6 * sizeof(float);
    float* partial = (float*)ws;           ws += NPART * sizeof(float);

    hipMemsetAsync(cnt, 0, (size_t)NG * NCELL * 4, stream);

    bbox_kernel<<<NG, THREADS, 0, stream>>>(ytrue, ypred, N, bbox);

    int ptBlocks = (int)((totalPts + THREADS - 1) / THREADS);
    hist_kernel<<<ptBlocks, THREADS, 0, stream>>>(ytrue, ypred, N, bbox, cnt);

    scan_kernel<<<NG, 1024, 0, stream>>>(cnt, sc);

    hipMemsetAsync(cnt, 0, (size_t)NG * NCELL * 4, stream);  // reuse as fill
    scatter_kernel<<<ptBlocks, THREADS, 0, stream>>>(ytrue, ypred, N, bbox, sc,
                                                     cnt, sorted);

    nn_kernel<<<ptBlocks, THREADS, 0, stream>>>(sorted, sc, bbox, N, res);

    reduce1_kernel<<<NPART, THREADS, 0, stream>>>(res, (int)totalPts, partial);
    reduce2_kernel<<<1, THREADS, 0, stream>>>(partial, NPART, 1.0f / BATCH,
                                              (float*)d_out);
}

// Round 3
// 486.026 us; speedup vs baseline: 3.4056x; 3.4056x over previous
//
#include <hip/hip_runtime.h>

#define BATCH 8
#define GDIM 32
#define GMASK (GDIM - 1)
#define NCELL (GDIM * GDIM * GDIM)   // 32768
#define NG (2 * BATCH)               // 16 grids: g = cloud*BATCH + b
#define THREADS 256
#define NSLAB GDIM                   // z-slabs per grid
#define SUBB 4                       // blocks per (grid,slab)
#define WPS (SUBB * 4)               // wave-slots per slab (4 waves/block)
#define CAP 320                      // LDS candidate-cell list entries per wave
#define ZEROBLK 512                  // blocks zeroing cnt in k1
#define NNBLOCKS (NSLAB * NG * SUBB) // 2048

// ---------------- helpers ----------------
__device__ __forceinline__ void gridParams(const float* bb, float lo[3],
                                           float inv[3], float cs[3]) {
#pragma unroll
    for (int d = 0; d < 3; ++d) {
        lo[d] = bb[d];
        float span = bb[3 + d] - bb[d];
        float iv = (float)GDIM / (span * (1.f + 1e-6f) + 1e-12f);
        inv[d] = iv;
        cs[d] = 1.f / iv;
    }
}

__device__ __forceinline__ int cellOf(float v, float lo, float inv) {
    return min(max((int)floorf((v - lo) * inv), 0), GDIM - 1);
}

__device__ __forceinline__ float axd(float v, float c0, float cw) {
    // distance from v to interval [c0, c0+cw], clamped at 0
    return fmaxf(fmaxf(c0 - v, v - (c0 + cw)), 0.f);
}

// ---------------- k1: per-grid bbox + zero cnt ----------------
__global__ __launch_bounds__(THREADS) void k1_bbox_zero(
    const float* __restrict__ ytrue, const float* __restrict__ ypred,
    int N, float* __restrict__ bbox, uint4* __restrict__ cntz)
{
    if (blockIdx.x >= NG) {
        int idx = (blockIdx.x - NG) * THREADS + threadIdx.x;
        cntz[idx] = make_uint4(0u, 0u, 0u, 0u);
        return;
    }
    int g = blockIdx.x;
    int cloud = g / BATCH, b = g % BATCH;
    const float* src = (cloud ? ypred : ytrue) + (size_t)b * N * 3;
    float mn[3] = {1e30f, 1e30f, 1e30f};
    float mx[3] = {-1e30f, -1e30f, -1e30f};
    for (int i = threadIdx.x; i < N; i += THREADS) {
        const float* p = src + (size_t)i * 3;
#pragma unroll
        for (int d = 0; d < 3; ++d) {
            float v = p[d];
            mn[d] = fminf(mn[d], v);
            mx[d] = fmaxf(mx[d], v);
        }
    }
#pragma unroll
    for (int off = 32; off > 0; off >>= 1) {
#pragma unroll
        for (int d = 0; d < 3; ++d) {
            mn[d] = fminf(mn[d], __shfl_down(mn[d], off, 64));
            mx[d] = fmaxf(mx[d], __shfl_down(mx[d], off, 64));
        }
    }
    __shared__ float sm[6][THREADS / 64];
    int w = threadIdx.x >> 6, l = threadIdx.x & 63;
    if (l == 0) {
#pragma unroll
        for (int d = 0; d < 3; ++d) { sm[d][w] = mn[d]; sm[3 + d][w] = mx[d]; }
    }
    __syncthreads();
    if (threadIdx.x == 0) {
#pragma unroll
        for (int k = 0; k < 6; ++k) {
            float v = sm[k][0];
            for (int i = 1; i < THREADS / 64; ++i)
                v = (k < 3) ? fminf(v, sm[k][i]) : fmaxf(v, sm[k][i]);
            bbox[g * 6 + k] = v;
        }
    }
}

// ---------------- k2: histogram ----------------
__global__ __launch_bounds__(THREADS) void k2_hist(
    const float* __restrict__ ytrue, const float* __restrict__ ypred,
    int N, const float* __restrict__ bbox, unsigned* __restrict__ cnt)
{
    int i = blockIdx.x * THREADS + threadIdx.x;
    if (i >= NG * N) return;
    int g = i / N, j = i - g * N;
    int cloud = g / BATCH, b = g % BATCH;
    const float* p = (cloud ? ypred : ytrue) + ((size_t)b * N + j) * 3;
    float lo[3], inv[3], cs[3];
    gridParams(bbox + g * 6, lo, inv, cs);
    int cx = cellOf(p[0], lo[0], inv[0]);
    int cy = cellOf(p[1], lo[1], inv[1]);
    int cz = cellOf(p[2], lo[2], inv[2]);
    atomicAdd(&cnt[(size_t)g * NCELL + (cz * GDIM + cy) * GDIM + cx], 1u);
}

// ---------------- k3: per-grid exclusive scan, pack (start<<16)|cnt, zero fill ----------------
__global__ __launch_bounds__(1024) void k3_scan(
    unsigned* __restrict__ cnt, unsigned* __restrict__ sc)
{
    int g = blockIdx.x;
    unsigned* c = cnt + (size_t)g * NCELL;
    unsigned* out = sc + (size_t)g * NCELL;
    const int per = NCELL / 1024;   // 32
    int base = threadIdx.x * per;
    unsigned lc[per];
    unsigned s = 0;
#pragma unroll
    for (int j = 0; j < per; ++j) { lc[j] = c[base + j]; s += lc[j]; }
    __shared__ unsigned sd[1024];
    sd[threadIdx.x] = s;
    __syncthreads();
    for (int off = 1; off < 1024; off <<= 1) {
        unsigned t = (threadIdx.x >= (unsigned)off) ? sd[threadIdx.x - off] : 0u;
        __syncthreads();
        sd[threadIdx.x] += t;
        __syncthreads();
    }
    unsigned run = sd[threadIdx.x] - s;
#pragma unroll
    for (int j = 0; j < per; ++j) {
        out[base + j] = (run << 16) | lc[j];
        run += lc[j];
        c[base + j] = 0u;   // becomes 'fill' for scatter
    }
}

// ---------------- k4: scatter into cell-sorted order, pack {x,y,z,|p|^2} ----------------
__global__ __launch_bounds__(THREADS) void k4_scatter(
    const float* __restrict__ ytrue, const float* __restrict__ ypred,
    int N, const float* __restrict__ bbox, const unsigned* __restrict__ sc,
    unsigned* __restrict__ fill, float4* __restrict__ sorted)
{
    int i = blockIdx.x * THREADS + threadIdx.x;
    if (i >= NG * N) return;
    int g = i / N, j = i - g * N;
    int cloud = g / BATCH, b = g % BATCH;
    const float* p = (cloud ? ypred : ytrue) + ((size_t)b * N + j) * 3;
    float x = p[0], y = p[1], z = p[2];
    float lo[3], inv[3], cs[3];
    gridParams(bbox + g * 6, lo, inv, cs);
    int cx = cellOf(x, lo[0], inv[0]);
    int cy = cellOf(y, lo[1], inv[1]);
    int cz = cellOf(z, lo[2], inv[2]);
    size_t cid = (size_t)g * NCELL + (cz * GDIM + cy) * GDIM + cx;
    unsigned st = sc[cid] >> 16;
    unsigned pos = st + atomicAdd(&fill[cid], 1u);
    sorted[(size_t)g * N + pos] =
        make_float4(x, y, z, fmaf(x, x, fmaf(y, y, z * z)));
}

// ---------------- k5: wave-cooperative exact NN ----------------
__global__ __launch_bounds__(THREADS) void k5_nn(
    const float4* __restrict__ sorted, const unsigned* __restrict__ sc,
    const float* __restrict__ bbox, int N, double* __restrict__ partial)
{
    __shared__ unsigned s_cid[4][CAP];
    __shared__ unsigned s_scv[4][CAP];
    __shared__ double s_red[4];

    const int wid  = threadIdx.x >> 6;
    const int lane = threadIdx.x & 63;
    unsigned* Lcid = s_cid[wid];
    unsigned* Lscv = s_scv[wid];

    int bid  = blockIdx.x;
    int slab = bid & (NSLAB - 1);
    int g    = (bid >> 5) & (NG - 1);
    int sub  = bid >> 9;              // 0..SUBB-1
    int w    = sub * 4 + wid;         // wave slot within slab, 0..WPS-1

    int cloud = g / BATCH, b = g - cloud * BATCH;
    int gr = (1 - cloud) * BATCH + b; // reference grid (the other cloud)

    float lo[3], inv[3], cs[3];
    gridParams(bbox + gr * 6, lo, inv, cs);
    const unsigned* __restrict__ C = sc + (size_t)gr * NCELL;
    const float4*  __restrict__ P  = sorted + (size_t)gr * N;

    unsigned sstart = sc[(size_t)g * NCELL + slab * (GDIM * GDIM)] >> 16;
    unsigned send   = (slab < NSLAB - 1)
        ? (sc[(size_t)g * NCELL + (slab + 1) * (GDIM * GDIM)] >> 16)
        : (unsigned)N;

    double acc = 0.0;

    for (unsigned q0 = sstart + (unsigned)w * 64u; q0 < send;
         q0 += (unsigned)WPS * 64u) {
        unsigned qi = q0 + (unsigned)lane;
        bool valid = qi < send;
        float4 q = make_float4(0.f, 0.f, 0.f, 0.f);
        if (valid) q = sorted[(size_t)g * N + qi];
        float q2 = q.w;
        float nqx = -2.f * q.x, nqy = -2.f * q.y, nqz = -2.f * q.z;
        float tb = 1e30f;   // best (d^2 - q2)

        int cx = cellOf(q.x, lo[0], inv[0]);
        int cy = cellOf(q.y, lo[1], inv[1]);
        int cz = cellOf(q.z, lo[2], inv[2]);

        int mnx = valid ? cx : 0x7fffffff, mxx = valid ? cx : -1;
        int mny = valid ? cy : 0x7fffffff, mxy = valid ? cy : -1;
        int mnz = valid ? cz : 0x7fffffff, mxz = valid ? cz : -1;
#pragma unroll
        for (int o = 32; o > 0; o >>= 1) {
            mnx = min(mnx, __shfl_xor(mnx, o, 64));
            mxx = max(mxx, __shfl_xor(mxx, o, 64));
            mny = min(mny, __shfl_xor(mny, o, 64));
            mxy = max(mxy, __shfl_xor(mxy, o, 64));
            mnz = min(mnz, __shfl_xor(mnz, o, 64));
            mxz = max(mxz, __shfl_xor(mxz, o, 64));
        }

        int x0 = max(mnx - 1, 0), x1 = min(mxx + 1, GDIM - 1);
        int y0 = max(mny - 1, 0), y1 = min(mxy + 1, GDIM - 1);
        int z0 = max(mnz - 1, 0), z1 = min(mxz + 1, GDIM - 1);
        int px0 = 1, px1 = 0, py0 = 1, py1 = 0, pz0 = 1, pz1 = 0;

        int len = 0;
        auto drain = [&]() {
            for (int e = 0; e < len; ++e) {
                unsigned cid = Lcid[e];
                unsigned scv = Lscv[e];
                int xx = cid & GMASK, yy = (cid >> 5) & GMASK, zz = cid >> 10;
                float dx = axd(q.x, lo[0] + xx * cs[0], cs[0]);
                float dy = axd(q.y, lo[1] + yy * cs[1], cs[1]);
                float dz = axd(q.z, lo[2] + zz * cs[2], cs[2]);
                float lb2 = fmaf(dx, dx, fmaf(dy, dy, dz * dz));
                bool want = valid && (lb2 * 0.999f < q2 + tb);
                if (__any(want)) {
                    unsigned st = scv >> 16;
                    unsigned jend = st + (scv & 0xffffu);
                    unsigned j = st;
                    for (; j + 2 <= jend; j += 2) {
                        float4 p0 = P[j], p1 = P[j + 1];
                        float t0 = fmaf(nqx, p0.x, fmaf(nqy, p0.y, fmaf(nqz, p0.z, p0.w)));
                        float t1 = fmaf(nqx, p1.x, fmaf(nqy, p1.y, fmaf(nqz, p1.z, p1.w)));
                        tb = fminf(tb, fminf(t0, t1));
                    }
                    if (j < jend) {
                        float4 p0 = P[j];
                        float t0 = fmaf(nqx, p0.x, fmaf(nqy, p0.y, fmaf(nqz, p0.z, p0.w)));
                        tb = fminf(tb, t0);
                    }
                }
            }
            len = 0;
        };

        for (;;) {
            // phase 1: wave-parallel cell-header loads, ballot-compact nonempty
            for (int z = z0; z <= z1; ++z) {
                for (int yb = y0; yb <= y1; yb += 2) {
                    int y = yb + (lane >> 5);
                    int x = x0 + (lane & 31);
                    bool cv = (y <= y1) && (x <= x1);
                    if (cv && x >= px0 && x <= px1 && y >= py0 && y <= py1 &&
                        z >= pz0 && z <= pz1)
                        cv = false;   // already visited in previous box
                    unsigned scv = 0u;
                    int cid = (z * GDIM + y) * GDIM + x;
                    if (cv) scv = C[cid];
                    bool ne = cv && (scv & 0xffffu) != 0u;
                    unsigned long long mask = __ballot((int)ne);
                    int nnew = __popcll(mask);
                    if (len + nnew > CAP) drain();
                    if (ne) {
                        int pos = len + __popcll(mask & ((1ull << lane) - 1ull));
                        Lcid[pos] = (unsigned)cid;
                        Lscv[pos] = scv;
                    }
                    len += nnew;
                }
            }
            drain();

            bool full = (x0 == 0 && y0 == 0 && z0 == 0 &&
                         x1 == GDIM - 1 && y1 == GDIM - 1 && z1 == GDIM - 1);
            if (full) break;
            // per-lane exact termination bound: dist to current box boundary
            float fx0 = lo[0] + x0 * cs[0], fx1 = lo[0] + (x1 + 1) * cs[0];
            float fy0 = lo[1] + y0 * cs[1], fy1 = lo[1] + (y1 + 1) * cs[1];
            float fz0 = lo[2] + z0 * cs[2], fz1 = lo[2] + (z1 + 1) * cs[2];
            float mx = fminf(x0 > 0 ? q.x - fx0 : 1e30f,
                             x1 < GDIM - 1 ? fx1 - q.x : 1e30f);
            float my = fminf(y0 > 0 ? q.y - fy0 : 1e30f,
                             y1 < GDIM - 1 ? fy1 - q.y : 1e30f);
            float mz = fminf(z0 > 0 ? q.z - fz0 : 1e30f,
                             z1 < GDIM - 1 ? fz1 - q.z : 1e30f);
            float m = fminf(mx, fminf(my, mz));
            bool done = !valid || (m > 0.f && m * m * 0.999f >= q2 + tb);
            if (__all((int)done)) break;
            px0 = x0; px1 = x1; py0 = y0; py1 = y1; pz0 = z0; pz1 = z1;
            x0 = max(x0 - 1, 0); x1 = min(x1 + 1, GDIM - 1);
            y0 = max(y0 - 1, 0); y1 = min(y1 + 1, GDIM - 1);
            z0 = max(z0 - 1, 0); z1 = min(z1 + 1, GDIM - 1);
        }

        if (valid) acc += (double)fmaxf(0.f, q2 + tb);
    }

#pragma unroll
    for (int o = 32; o > 0; o >>= 1) acc += __shfl_down(acc, o, 64);
    if (lane == 0) s_red[wid] = acc;
    __syncthreads();
    if (threadIdx.x == 0)
        partial[bid] = s_red[0] + s_red[1] + s_red[2] + s_red[3];
}

// ---------------- k6: final deterministic-enough (double) reduction ----------------
__global__ __launch_bounds__(THREADS) void k6_final(
    const double* __restrict__ partial, float* __restrict__ out)
{
    double s = 0.0;
    for (int i = threadIdx.x; i < NNBLOCKS; i += THREADS) s += partial[i];
#pragma unroll
    for (int o = 32; o > 0; o >>= 1) s += __shfl_down(s, o, 64);
    __shared__ double sd[4];
    int wid = threadIdx.x >> 6, lane = threadIdx.x & 63;
    if (lane == 0) sd[wid] = s;
    __syncthreads();
    if (threadIdx.x == 0)
        out[0] = (float)((sd[0] + sd[1] + sd[2] + sd[3]) / (double)BATCH);
}

extern "C" void kernel_launch(void* const* d_in, const int* in_sizes, int n_in,
                              void* d_out, int out_size, void* d_ws, size_t ws_size,
                              hipStream_t stream)
{
    const float* ytrue = (const float*)d_in[0];
    const float* ypred = (const float*)d_in[1];
    int N = in_sizes[0] / (BATCH * 3);          // 8192
    size_t total = (size_t)NG * N;              // 131072

    char* ws = (char*)d_ws;
    float4*   sorted  = (float4*)ws;   ws += total * sizeof(float4);        // 2 MB
    unsigned* cnt     = (unsigned*)ws; ws += (size_t)NG * NCELL * 4;        // 2 MB
    unsigned* sc      = (unsigned*)ws; ws += (size_t)NG * NCELL * 4;        // 2 MB
    double*   partial = (double*)ws;   ws += (size_t)NNBLOCKS * 8;          // 16 KB
    float*    bbox    = (float*)ws;    ws += NG * 6 * sizeof(float);

    k1_bbox_zero<<<NG + ZEROBLK, THREADS, 0, stream>>>(ytrue, ypred, N, bbox,
                                                       (uint4*)cnt);
    int ptB = (int)((total + THREADS - 1) / THREADS);
    k2_hist<<<ptB, THREADS, 0, stream>>>(ytrue, ypred, N, bbox, cnt);
    k3_scan<<<NG, 1024, 0, stream>>>(cnt, sc);
    k4_scatter<<<ptB, THREADS, 0, stream>>>(ytrue, ypred, N, bbox, sc, cnt,
                                            sorted);
    k5_nn<<<NNBLOCKS, THREADS, 0, stream>>>(sorted, sc, bbox, N, partial);
    k6_final<<<1, THREADS, 0, stream>>>(partial, (float*)d_out);
}

// Round 4
// 353.793 us; speedup vs baseline: 4.6785x; 1.3738x over previous
//
#include <hip/hip_runtime.h>

#define BATCH 8
#define GDIM 32
#define NCELL (GDIM * GDIM * GDIM)   // 32768
#define NG (2 * BATCH)               // 16 grids
#define K5BLK 512                    // blocks in k5 (4 waves each -> 2048 groups)

// ---------------- helpers ----------------
__device__ __forceinline__ void gridParams(const float* bb, float lo[3],
                                           float inv[3], float cs[3]) {
#pragma unroll
    for (int d = 0; d < 3; ++d) {
        lo[d] = bb[d];
        float span = bb[3 + d] - bb[d];
        float iv = (float)GDIM / (span * (1.f + 1e-6f) + 1e-12f);
        inv[d] = iv;
        cs[d] = 1.f / iv;
    }
}

__device__ __forceinline__ int cellOf(float v, float lo, float inv) {
    return min(max((int)floorf((v - lo) * inv), 0), GDIM - 1);
}

__device__ __forceinline__ float axd(float v, float c0, float cw) {
    return fmaxf(fmaxf(c0 - v, v - (c0 + cw)), 0.f);
}

// decode 4 packed points from 3 float4s
__device__ __forceinline__ void get4pts(const float4& f0, const float4& f1,
                                        const float4& f2, float px[4],
                                        float py[4], float pz[4]) {
    px[0] = f0.x; py[0] = f0.y; pz[0] = f0.z;
    px[1] = f0.w; py[1] = f1.x; pz[1] = f1.y;
    px[2] = f1.z; py[2] = f1.w; pz[2] = f2.x;
    px[3] = f2.y; py[3] = f2.z; pz[3] = f2.w;
}

// ---------------- k1: bbox (blocks 0..NG-1) + zero cnt (rest) ----------------
__global__ __launch_bounds__(256) void k1_bbox_zero(
    const float* __restrict__ ytrue, const float* __restrict__ ypred,
    int N, float* __restrict__ bbox, uint4* __restrict__ cntz)
{
    if (blockIdx.x >= NG) {
        cntz[(blockIdx.x - NG) * 256 + threadIdx.x] = make_uint4(0, 0, 0, 0);
        return;
    }
    int g = blockIdx.x;
    int cloud = g >> 3, b = g & 7;
    const float4* src4 = (const float4*)((cloud ? ypred : ytrue) + (size_t)b * N * 3);
    int nquad = N >> 2;
    float mn[3] = {1e30f, 1e30f, 1e30f}, mx[3] = {-1e30f, -1e30f, -1e30f};
    for (int qk = threadIdx.x; qk < nquad; qk += 256) {
        float4 f0 = src4[3 * qk], f1 = src4[3 * qk + 1], f2 = src4[3 * qk + 2];
        float px[4], py[4], pz[4];
        get4pts(f0, f1, f2, px, py, pz);
#pragma unroll
        for (int k = 0; k < 4; ++k) {
            mn[0] = fminf(mn[0], px[k]); mx[0] = fmaxf(mx[0], px[k]);
            mn[1] = fminf(mn[1], py[k]); mx[1] = fmaxf(mx[1], py[k]);
            mn[2] = fminf(mn[2], pz[k]); mx[2] = fmaxf(mx[2], pz[k]);
        }
    }
#pragma unroll
    for (int o = 32; o; o >>= 1) {
#pragma unroll
        for (int d = 0; d < 3; ++d) {
            mn[d] = fminf(mn[d], __shfl_down(mn[d], o, 64));
            mx[d] = fmaxf(mx[d], __shfl_down(mx[d], o, 64));
        }
    }
    __shared__ float sm[6][4];
    int w = threadIdx.x >> 6, l = threadIdx.x & 63;
    if (l == 0) {
#pragma unroll
        for (int d = 0; d < 3; ++d) { sm[d][w] = mn[d]; sm[3 + d][w] = mx[d]; }
    }
    __syncthreads();
    if (threadIdx.x == 0) {
#pragma unroll
        for (int k = 0; k < 6; ++k) {
            float v = sm[k][0];
#pragma unroll
            for (int i = 1; i < 4; ++i)
                v = (k < 3) ? fminf(v, sm[k][i]) : fmaxf(v, sm[k][i]);
            bbox[g * 6 + k] = v;
        }
    }
}

// ---------------- k2: histogram (float4 loads, 4 pts/thread) ----------------
__global__ __launch_bounds__(256) void k2_hist(
    const float* __restrict__ ytrue, const float* __restrict__ ypred,
    int N, const float* __restrict__ bbox, unsigned* __restrict__ cnt)
{
    int nquad = N >> 2;
    int bpg = nquad >> 8;                 // blocks per grid (8)
    int g = blockIdx.x / bpg;
    int qk = (blockIdx.x - g * bpg) * 256 + threadIdx.x;
    int cloud = g >> 3, b = g & 7;
    const float4* src4 = (const float4*)((cloud ? ypred : ytrue) + (size_t)b * N * 3);
    float lo[3], inv[3], cs[3];
    gridParams(bbox + g * 6, lo, inv, cs);
    float4 f0 = src4[3 * qk], f1 = src4[3 * qk + 1], f2 = src4[3 * qk + 2];
    float px[4], py[4], pz[4];
    get4pts(f0, f1, f2, px, py, pz);
    unsigned* Cg = cnt + (size_t)g * NCELL;
#pragma unroll
    for (int k = 0; k < 4; ++k) {
        int cx = cellOf(px[k], lo[0], inv[0]);
        int cy = cellOf(py[k], lo[1], inv[1]);
        int cz = cellOf(pz[k], lo[2], inv[2]);
        atomicAdd(&Cg[(cz * GDIM + cy) * GDIM + cx], 1u);
    }
}

// ---------------- k3: per-grid scan over 32768 cells (row-per-thread) ----------------
__global__ __launch_bounds__(1024) void k3_scan(
    unsigned* __restrict__ cnt, unsigned* __restrict__ sc)
{
    int g = blockIdx.x;
    unsigned* c = cnt + (size_t)g * NCELL;
    unsigned* out = sc + (size_t)g * NCELL;
    int t = threadIdx.x;
    uint4 v[8];
    const uint4* c4 = (const uint4*)(c + t * 32);
    unsigned sum = 0;
#pragma unroll
    for (int j = 0; j < 8; ++j) {
        v[j] = c4[j];
        sum += v[j].x + v[j].y + v[j].z + v[j].w;
    }
    __shared__ unsigned sd[1024];
    sd[t] = sum;
    __syncthreads();
    unsigned val = sum;
    for (int off = 1; off < 1024; off <<= 1) {
        unsigned o = (t >= off) ? sd[t - off] : 0u;
        __syncthreads();
        val += o;
        sd[t] = val;
        __syncthreads();
    }
    unsigned run = val - sum;   // exclusive prefix of this row
    uint4* o4 = (uint4*)(out + t * 32);
    uint4* z4 = (uint4*)(c + t * 32);
#pragma unroll
    for (int j = 0; j < 8; ++j) {
        uint4 w;
        w.x = (run << 16) | v[j].x; run += v[j].x;
        w.y = (run << 16) | v[j].y; run += v[j].y;
        w.z = (run << 16) | v[j].z; run += v[j].z;
        w.w = (run << 16) | v[j].w; run += v[j].w;
        o4[j] = w;
        z4[j] = make_uint4(0, 0, 0, 0);   // becomes 'fill'
    }
}

// ---------------- k4: scatter (float4 loads, 4 pts/thread) ----------------
__global__ __launch_bounds__(256) void k4_scatter(
    const float* __restrict__ ytrue, const float* __restrict__ ypred,
    int N, const float* __restrict__ bbox, const unsigned* __restrict__ sc,
    unsigned* __restrict__ fill, float4* __restrict__ sorted)
{
    int nquad = N >> 2;
    int bpg = nquad >> 8;
    int g = blockIdx.x / bpg;
    int qk = (blockIdx.x - g * bpg) * 256 + threadIdx.x;
    int cloud = g >> 3, b = g & 7;
    const float4* src4 = (const float4*)((cloud ? ypred : ytrue) + (size_t)b * N * 3);
    float lo[3], inv[3], cs[3];
    gridParams(bbox + g * 6, lo, inv, cs);
    float4 f0 = src4[3 * qk], f1 = src4[3 * qk + 1], f2 = src4[3 * qk + 2];
    float px[4], py[4], pz[4];
    get4pts(f0, f1, f2, px, py, pz);
    const unsigned* Sg = sc + (size_t)g * NCELL;
    unsigned* Fg = fill + (size_t)g * NCELL;
    float4* Og = sorted + (size_t)g * N;
#pragma unroll
    for (int k = 0; k < 4; ++k) {
        int cx = cellOf(px[k], lo[0], inv[0]);
        int cy = cellOf(py[k], lo[1], inv[1]);
        int cz = cellOf(pz[k], lo[2], inv[2]);
        int cid = (cz * GDIM + cy) * GDIM + cx;
        unsigned pos = (Sg[cid] >> 16) + atomicAdd(&Fg[cid], 1u);
        Og[pos] = make_float4(px[k], py[k], pz[k],
                              fmaf(px[k], px[k], fmaf(py[k], py[k], pz[k] * pz[k])));
    }
}

// ---------------- k5: wave-cooperative exact NN, row-segment staging ----------------
__global__ __launch_bounds__(256) void k5_nn(
    const float4* __restrict__ sorted, const unsigned* __restrict__ sc,
    const float* __restrict__ bbox, int N, double* __restrict__ partial)
{
    __shared__ float4 stage[4][64];
    __shared__ double s_red[4];
    const int wid = threadIdx.x >> 6, lane = threadIdx.x & 63;
    const int ngpg = N >> 6;                           // groups per grid (128)
    int group = (int)blockIdx.x + (int)gridDim.x * wid; // strided: mixes heavy/light
    int g = group / ngpg;
    int q0 = (group - g * ngpg) << 6;
    int cloud = g >> 3, b = g & 7;
    int gr = ((1 - cloud) << 3) | b;

    float lo[3], inv[3], cs[3];
    gridParams(bbox + gr * 6, lo, inv, cs);
    const unsigned* __restrict__ C = sc + (size_t)gr * NCELL;
    const float4* __restrict__ P = sorted + (size_t)gr * N;

    float4 q = sorted[(size_t)g * N + q0 + lane];   // N % 64 == 0
    float q2 = q.w;
    float nqx = -2.f * q.x, nqy = -2.f * q.y, nqz = -2.f * q.z;
    float tb = 1e30f;                                // best (d^2 - q2)

    int cx = cellOf(q.x, lo[0], inv[0]);
    int cy = cellOf(q.y, lo[1], inv[1]);
    int cz = cellOf(q.z, lo[2], inv[2]);
    int mnx = cx, mxx = cx, mny = cy, mxy = cy, mnz = cz, mxz = cz;
#pragma unroll
    for (int o = 32; o; o >>= 1) {
        mnx = min(mnx, __shfl_xor(mnx, o, 64)); mxx = max(mxx, __shfl_xor(mxx, o, 64));
        mny = min(mny, __shfl_xor(mny, o, 64)); mxy = max(mxy, __shfl_xor(mxy, o, 64));
        mnz = min(mnz, __shfl_xor(mnz, o, 64)); mxz = max(mxz, __shfl_xor(mxz, o, 64));
    }
    int x0 = __builtin_amdgcn_readfirstlane(max(mnx - 1, 0));
    int x1 = __builtin_amdgcn_readfirstlane(min(mxx + 1, GDIM - 1));
    int y0 = __builtin_amdgcn_readfirstlane(max(mny - 1, 0));
    int y1 = __builtin_amdgcn_readfirstlane(min(mxy + 1, GDIM - 1));
    int z0 = __builtin_amdgcn_readfirstlane(max(mnz - 1, 0));
    int z1 = __builtin_amdgcn_readfirstlane(min(mxz + 1, GDIM - 1));
    int px0 = 0, px1 = -1, py0 = 0, py1 = -1, pz0 = 0, pz1 = -1;  // prev box empty

    float4* S = stage[wid];

    auto rangeTest = [&](unsigned a, unsigned bnd, int xa, int xb, float dyz2) {
        if (a >= bnd) return;
        float cw = (float)(xb - xa + 1) * cs[0];
        float dx = axd(q.x, lo[0] + xa * cs[0], cw);
        float lb2 = fmaf(dx, dx, dyz2);
        if (!__any(lb2 * 0.999f < q2 + tb)) return;
        for (unsigned cb = a; cb < bnd; cb += 64) {
            unsigned ci = cb + lane;
            if (ci < bnd) S[lane] = P[ci];
            int nk = min(64, (int)(bnd - cb));
            float t0 = 1e30f, t1 = 1e30f;
            int k = 0;
#pragma unroll 4
            for (; k + 2 <= nk; k += 2) {
                float4 pa = S[k], pb = S[k + 1];
                float ta = fmaf(nqx, pa.x, fmaf(nqy, pa.y, fmaf(nqz, pa.z, pa.w)));
                float tc = fmaf(nqx, pb.x, fmaf(nqy, pb.y, fmaf(nqz, pb.z, pb.w)));
                t0 = fminf(t0, ta);
                t1 = fminf(t1, tc);
            }
            if (k < nk) {
                float4 pa = S[k];
                t0 = fminf(t0, fmaf(nqx, pa.x, fmaf(nqy, pa.y, fmaf(nqz, pa.z, pa.w))));
            }
            tb = fminf(tb, fminf(t0, t1));
        }
    };

    for (;;) {   // shell-expansion passes
        int ny = y1 - y0 + 1;
        int nrows = (z1 - z0 + 1) * ny;
        int zw = z0, yw = y0;   // scalar row walker
        for (int r0 = 0; r0 < nrows; r0 += 64) {
            // wave-parallel header gather for rows r0..r0+63
            int rr = min(r0 + lane, nrows - 1);
            int zq = rr / ny;
            int zi = z0 + zq;
            int yi = y0 + (rr - zq * ny);
            const unsigned* rowp = C + (zi * GDIM + yi) * GDIM;
            unsigned hA = rowp[x0];
            unsigned hB = rowp[x1];
            bool prowL = (zi >= pz0 && zi <= pz1 && yi >= py0 && yi <= py1);
            unsigned hP0 = 0u, hP1 = 0u;
            if (prowL) { hP0 = rowp[px0]; hP1 = rowp[px1]; }
            int rend = min(64, nrows - r0);
            for (int ri = 0; ri < rend; ++ri) {
                unsigned ha = (unsigned)__builtin_amdgcn_readlane((int)hA, ri);
                unsigned hb = (unsigned)__builtin_amdgcn_readlane((int)hB, ri);
                unsigned rs = ha >> 16;
                unsigned re = (hb >> 16) + (hb & 0xffffu);
                if (rs != re) {
                    float dz = axd(q.z, lo[2] + zw * cs[2], cs[2]);
                    float dy = axd(q.y, lo[1] + yw * cs[1], cs[1]);
                    float dyz2 = fmaf(dy, dy, dz * dz);
                    bool pr = (zw >= pz0 && zw <= pz1 && yw >= py0 && yw <= py1);
                    if (pr) {
                        unsigned hp0 = (unsigned)__builtin_amdgcn_readlane((int)hP0, ri);
                        unsigned hp1 = (unsigned)__builtin_amdgcn_readlane((int)hP1, ri);
                        unsigned es = hp0 >> 16;
                        unsigned ee = (hp1 >> 16) + (hp1 & 0xffffu);
                        rangeTest(rs, es, x0, px0 - 1, dyz2);
                        rangeTest(ee, re, px1 + 1, x1, dyz2);
                    } else {
                        rangeTest(rs, re, x0, x1, dyz2);
                    }
                }
                if (++yw > y1) { yw = y0; ++zw; }
            }
        }
        // termination: per-lane distance to box faces (skip grid-edge faces)
        float dbest = q2 + tb;
        float mx = fminf(x0 > 0 ? q.x - (lo[0] + x0 * cs[0]) : 1e30f,
                         x1 < GDIM - 1 ? (lo[0] + (x1 + 1) * cs[0]) - q.x : 1e30f);
        float my = fminf(y0 > 0 ? q.y - (lo[1] + y0 * cs[1]) : 1e30f,
                         y1 < GDIM - 1 ? (lo[1] + (y1 + 1) * cs[1]) - q.y : 1e30f);
        float mz = fminf(z0 > 0 ? q.z - (lo[2] + z0 * cs[2]) : 1e30f,
                         z1 < GDIM - 1 ? (lo[2] + (z1 + 1) * cs[2]) - q.z : 1e30f);
        float m = fminf(mx, fminf(my, mz));
        bool done = (m > 0.f) && (m * m * 0.999f >= dbest);
        bool full = (x0 == 0 && y0 == 0 && z0 == 0 &&
                     x1 == GDIM - 1 && y1 == GDIM - 1 && z1 == GDIM - 1);
        if (full || __all((int)done)) break;
        px0 = x0; px1 = x1; py0 = y0; py1 = y1; pz0 = z0; pz1 = z1;
        x0 = max(x0 - 1, 0); x1 = min(x1 + 1, GDIM - 1);
        y0 = max(y0 - 1, 0); y1 = min(y1 + 1, GDIM - 1);
        z0 = max(z0 - 1, 0); z1 = min(z1 + 1, GDIM - 1);
    }

    double acc = (double)fmaxf(0.f, q2 + tb);
#pragma unroll
    for (int o = 32; o; o >>= 1) acc += __shfl_down(acc, o, 64);
    if (lane == 0) s_red[wid] = acc;
    __syncthreads();
    if (threadIdx.x == 0)
        partial[blockIdx.x] = s_red[0] + s_red[1] + s_red[2] + s_red[3];
}

// ---------------- k6: final reduction ----------------
__global__ __launch_bounds__(256) void k6_final(
    const double* __restrict__ partial, int n, float* __restrict__ out)
{
    double s = 0.0;
    for (int i = threadIdx.x; i < n; i += 256) s += partial[i];
#pragma unroll
    for (int o = 32; o; o >>= 1) s += __shfl_down(s, o, 64);
    __shared__ double sd[4];
    int wid = threadIdx.x >> 6, lane = threadIdx.x & 63;
    if (lane == 0) sd[wid] = s;
    __syncthreads();
    if (threadIdx.x == 0)
        out[0] = (float)((sd[0] + sd[1] + sd[2] + sd[3]) / (double)BATCH);
}

extern "C" void kernel_launch(void* const* d_in, const int* in_sizes, int n_in,
                              void* d_out, int out_size, void* d_ws, size_t ws_size,
                              hipStream_t stream)
{
    const float* ytrue = (const float*)d_in[0];
    const float* ypred = (const float*)d_in[1];
    int N = in_sizes[0] / (BATCH * 3);          // 8192
    size_t total = (size_t)NG * N;              // 131072

    char* ws = (char*)d_ws;
    float4*   sorted  = (float4*)ws;   ws += total * sizeof(float4);   // 2 MB
    unsigned* cnt     = (unsigned*)ws; ws += (size_t)NG * NCELL * 4;   // 2 MB (fill)
    unsigned* sc      = (unsigned*)ws; ws += (size_t)NG * NCELL * 4;   // 2 MB
    double*   partial = (double*)ws;   ws += (size_t)K5BLK * 8;
    float*    bbox    = (float*)ws;    ws += NG * 6 * sizeof(float);

    // zero blocks: NG*NCELL uints / (256 threads * uint4) = 512 blocks
    k1_bbox_zero<<<NG + 512, 256, 0, stream>>>(ytrue, ypred, N, bbox, (uint4*)cnt);

    int ptB = (int)(total / 4 / 256);           // 128 blocks
    k2_hist<<<ptB, 256, 0, stream>>>(ytrue, ypred, N, bbox, cnt);
    k3_scan<<<NG, 1024, 0, stream>>>(cnt, sc);
    k4_scatter<<<ptB, 256, 0, stream>>>(ytrue, ypred, N, bbox, sc, cnt, sorted);
    k5_nn<<<K5BLK, 256, 0, stream>>>(sorted, sc, bbox, N, partial);
    k6_final<<<1, 256, 0, stream>>>(partial, K5BLK, (float*)d_out);
}